// Round 1
// baseline (178.979 us; speedup 1.0000x reference)
//
#include <hip/hip_runtime.h>
#include <math.h>

#define BSZ   8
#define NSEQ  1024
#define DIM   512
#define NH    8
#define DH    64
#define INNER 512
#define NTOK  (BSZ*NSEQ)     // 8192
#define QKVN  (3*INNER)      // 1536

typedef __bf16 bf16x8 __attribute__((ext_vector_type(8)));
typedef float  f32x4  __attribute__((ext_vector_type(4)));

// q pre-scale: softmax scale (DH^-0.5 = 0.125) folded with log2(e)
#define QSCL (0.125f * 1.44269504088896f)

// attn LDS layout: 3 K/V buffers of 16384, then P region
#define ATTN_P_OFF 49152
#define ATTN_LDS   67584

static __device__ __forceinline__ ushort f2bf(float f) {
    union { float f; unsigned u; } v; v.f = f;
    unsigned r = (v.u + 0x7FFFu + ((v.u >> 16) & 1u)) >> 16;  // RNE
    return (ushort)r;
}
static __device__ __forceinline__ float bf2f(ushort u) {
    union { unsigned u; float f; } v; v.u = ((unsigned)u) << 16;
    return v.f;
}
static __device__ __forceinline__ void split2(float x, ushort& h, ushort& l) {
    h = f2bf(x);
    l = f2bf(x - bf2f(h));
}
// async global->LDS DMA, 16B per lane; LDS dest = wave-uniform base + lane*16
static __device__ __forceinline__ void async16(const void* g, void* l) {
    __builtin_amdgcn_global_load_lds(
        (const __attribute__((address_space(1))) unsigned int*)g,
        (__attribute__((address_space(3))) unsigned int*)l, 16, 0, 0);
}

// ---------------------------------------------------------------------------
// Elementwise fp32 -> bf16 hi/lo split (x)
// ---------------------------------------------------------------------------
__global__ __launch_bounds__(256) void split_cvt_kernel(
    const float* __restrict__ in, ushort* __restrict__ oh, ushort* __restrict__ ol)
{
    const int i = blockIdx.x * 256 + threadIdx.x;
    float4 v = ((const float4*)in)[i];
    ushort4 h, l;
    split2(v.x, h.x, l.x); split2(v.y, h.y, l.y);
    split2(v.z, h.z, l.z); split2(v.w, h.w, l.w);
    ((ushort4*)oh)[i] = h;
    ((ushort4*)ol)[i] = l;
}

// ---------------------------------------------------------------------------
// Transpose + convert: in [K][F] fp32 row-major -> out [F][K] bf16
// ---------------------------------------------------------------------------
__global__ __launch_bounds__(256) void tconv_kernel(
    const float* __restrict__ in, ushort* __restrict__ outh, int K, int F)
{
    __shared__ float tile[32][33];
    const int bx = blockIdx.x;           // F/32
    const int by = blockIdx.y;           // K/32
    const int lx = threadIdx.x & 31, ly = threadIdx.x >> 5;
#pragma unroll
    for (int u = 0; u < 4; u++) {
        const int k = by*32 + ly + u*8;
        tile[ly + u*8][lx] = in[(size_t)k*F + bx*32 + lx];
    }
    __syncthreads();
#pragma unroll
    for (int u = 0; u < 4; u++) {
        const int f = bx*32 + ly + u*8;
        outh[(size_t)f*K + by*32 + lx] = f2bf(tile[lx][ly + u*8]);
    }
}

// ---------------------------------------------------------------------------
// Kernel 1: qkv^T MFMA GEMM: C = w_bf16 * (xh + xl), 2 passes, 3 staged
// parts (Ah/Bh/Bl), BK=32.
// R14: TRIPLE-buffered LDS (3 x 24576 = 73728 B), ONE barrier per chunk,
// 2-chunk-deep DMA prefetch. Stage(ch+2) is issued right after barrier(ch):
// safe because all waves passed barrier(ch) => all consumed buf (ch-1)%3,
// which is the buffer being overwritten; compute buf ch%3 and in-flight
// buf (ch+1)%3 are distinct mod 3.
// Epilogue: bias + SE(3) pose; q,k row-major; V written transposed to vt.
// ---------------------------------------------------------------------------
__global__ __launch_bounds__(256) void qkv_gemm_split(
    const ushort* __restrict__ Agh, const ushort* __restrict__ Bgh,
    const ushort* __restrict__ Bgl,
    const float* __restrict__ bias, const float* __restrict__ rot,
    const float* __restrict__ trans,
    ushort* __restrict__ qb, ushort* __restrict__ kb, ushort* __restrict__ vt)
{
    extern __shared__ __align__(16) char smem[];   // 73728 B (3 x 24576)

    const int tid  = threadIdx.x;
    const int lane = tid & 63;
    const int w    = tid >> 6;
    const int c    = lane & 15;
    const int quad = lane >> 4;
    const int wr   = w >> 1, wc = w & 1;
    const int tn   = blockIdx.x;   // token tile (64)
    const int tf   = blockIdx.y;   // feature tile (12)

    f32x4 acc[4][4] = {};

    // wave roles: 0 -> Ah, 1 -> Bh, 2 -> Bl, 3 -> idle (issue-only staging)
    const ushort* wp = (w == 0) ? Agh : (w == 1) ? Bgh : Bgl;
    const ushort* wbase = wp + (size_t)((w == 0 ? tf : tn)*128 + c)*DIM + quad*8;
    const int lbase = w * 8192;    // A at 0, Bh at 8192, Bl at 16384

    auto stage = [&](int k0, int buf) {
        if (w < 3) {
#pragma unroll
            for (int g = 0; g < 8; g++)
                async16(wbase + (size_t)g*16*DIM + k0,
                        smem + buf*24576 + lbase + g*1024);
        }
    };

    stage(0, 0);
    stage(32, 1);

    for (int ch = 0; ch < 16; ch++) {
        const int cur = ch % 3;
        // own chunk-ch DMAs done (8 younger stay in flight), then sync so
        // every wave's chunk-ch data is visible in LDS
        if (ch < 15) {
            __asm__ volatile("s_waitcnt vmcnt(8)\n\ts_barrier" ::: "memory");
        } else {
            __asm__ volatile("s_waitcnt vmcnt(0)\n\ts_barrier" ::: "memory");
        }
        // prefetch 2 chunks ahead into buf (ch+2)%3 == (ch-1)%3 (now free)
        if (ch < 14) stage((ch+2)*32, (ch+2) % 3);

        const char* B = smem + cur*24576;
        bf16x8 fa[4], fbh[4], fbl[4];
#pragma unroll
        for (int i = 0; i < 4; i++)
            fa[i] = *(const bf16x8*)(B + (wr*4 + i)*1024 + lane*16);
#pragma unroll
        for (int j = 0; j < 4; j++) {
            fbh[j] = *(const bf16x8*)(B +  8192 + (wc*4 + j)*1024 + lane*16);
            fbl[j] = *(const bf16x8*)(B + 16384 + (wc*4 + j)*1024 + lane*16);
        }
#pragma unroll
        for (int i = 0; i < 4; i++)
#pragma unroll
            for (int j = 0; j < 4; j++) {
                acc[i][j] = __builtin_amdgcn_mfma_f32_16x16x32_bf16(
                    fa[i], fbh[j], acc[i][j], 0, 0, 0);
                acc[i][j] = __builtin_amdgcn_mfma_f32_16x16x32_bf16(
                    fa[i], fbl[j], acc[i][j], 0, 0, 0);
            }
        // no trailing barrier: next overwrite of buf cur is gated by the
        // top-of-loop barrier two iterations from now
    }

    // epilogue: bias + SE(3) pose + scatter (verified mapping)
    const int sec = tf >> 2;          // 0=q 1=k 2=v (block-uniform)

#pragma unroll
    for (int j = 0; j < 4; j++) {
        const int tc = tn*128 + wc*64 + j*16 + c;
        const int bb = tc >> 10, n = tc & 1023;
        const float* R = rot   + (size_t)(bb*NSEQ + n)*9;
        const float* T = trans + (size_t)(bb*NSEQ + n)*3;
        const float R0=R[0],R1=R[1],R2=R[2],R3=R[3],R4=R[4],R5=R[5],R6=R[6],R7=R[7],R8=R[8];
        const float T0=T[0],T1=T[1],T2=T[2];
        float ti0 = 0.f, ti1 = 0.f, ti2 = 0.f;
        if (sec == 0) {
            ti0 = -(R0*T0 + R3*T1 + R6*T2);
            ti1 = -(R1*T0 + R4*T1 + R7*T2);
            ti2 = -(R2*T0 + R5*T1 + R8*T2);
        }
#pragma unroll
        for (int i = 0; i < 4; i++) {
            const int fr = tf*128 + wr*64 + i*16 + quad*4;
            const int fl = fr & 511;
            const int h  = fl >> 6, d = fl & 63;
            float4 bv = *(const float4*)(bias + fr);
            const float g0 = acc[i][j][0] + bv.x;
            const float g1 = acc[i][j][1] + bv.y;
            const float g2 = acc[i][j][2] + bv.z;
            const float g3 = acc[i][j][3] + bv.w;
            if (sec == 0) {
                float o0 = (R0*g0 + R1*g1 + R2*g2) * QSCL;
                float o1 = (R3*g0 + R4*g1 + R5*g2) * QSCL;
                float o2 = (R6*g0 + R7*g1 + R8*g2) * QSCL;
                float o3 = (ti0*g0 + ti1*g1 + ti2*g2 + g3) * QSCL;
                ushort4 ov = { f2bf(o0), f2bf(o1), f2bf(o2), f2bf(o3) };
                *(ushort4*)(qb + ((size_t)((bb*NH + h)*NSEQ + n))*DH + d) = ov;
            } else {
                float o0 = R0*g0 + R1*g1 + R2*g2 + T0*g3;
                float o1 = R3*g0 + R4*g1 + R5*g2 + T1*g3;
                float o2 = R6*g0 + R7*g1 + R8*g2 + T2*g3;
                float o3 = g3;
                if (sec == 1) {
                    ushort4 ov = { f2bf(o0), f2bf(o1), f2bf(o2), f2bf(o3) };
                    *(ushort4*)(kb + ((size_t)((bb*NH + h)*NSEQ + n))*DH + d) = ov;
                } else {
                    // v: write TRANSPOSED -> vt[bh][d][n]
                    ushort* vtb = vt + ((size_t)(bb*NH + h)*DH + d)*NSEQ + n;
                    vtb[0*NSEQ] = f2bf(o0);
                    vtb[1*NSEQ] = f2bf(o1);
                    vtb[2*NSEQ] = f2bf(o2);
                    vtb[3*NSEQ] = f2bf(o3);
                }
            }
        }
    }
}

// ---------------------------------------------------------------------------
// Kernel 2: async-pipelined MFMA flash attention.
// R14: TRIPLE-buffered K/V LDS (3 x 16384), ONE barrier per kt, 2-deep
// prefetch. P region moved to +49152 (per-wave, no cross-wave hazard).
// Dynamic LDS = 67584 B (2 blocks/CU — matches grid of 2 blocks/CU).
// ---------------------------------------------------------------------------
__global__ __launch_bounds__(256) void attn_mfma_kernel(
    const ushort* __restrict__ qb, const ushort* __restrict__ kb,
    const ushort* __restrict__ vt, const float* __restrict__ rot,
    const float* __restrict__ trans, ushort* __restrict__ om)
{
    extern __shared__ __align__(16) char smem[];   // 67584 B

    const int tid  = threadIdx.x;
    const int lane = tid & 63;
    const int w    = tid >> 6;
    const int c    = lane & 15;
    const int quad = lane >> 4;

    const int qt = blockIdx.x;      // 0..7 (128 q rows)
    const int bh = blockIdx.y;      // 0..63
    const int bb = bh >> 3, h = bh & 7;

    const ushort* Q = qb + (size_t)bh * NSEQ * DH;
    const ushort* K = kb + (size_t)bh * NSEQ * DH;
    const ushort* V = vt + (size_t)bh * DH * NSEQ;   // [DH][NSEQ]

    bf16x8 qf[2][2];
#pragma unroll
    for (int m = 0; m < 2; m++) {
        const ushort* qrow = Q + (size_t)(qt*128 + w*32 + m*16 + c)*DH + quad*8;
        qf[m][0] = *(const bf16x8*)(qrow);
        qf[m][1] = *(const bf16x8*)(qrow + 32);
    }

    f32x4 Oacc[2][4] = {};
    float lsum[2][4] = {};

    auto stage = [&](int kt, int buf) {
#pragma unroll
        for (int u = 0; u < 2; u++) {            // K segs
            const int seg = w + u*4;             // 0..7
            const int nt = seg >> 1, hh = seg & 1;
            const ushort* g = K + (size_t)(kt*64 + nt*16 + c)*DH + hh*32 + quad*8;
            async16(g, smem + buf*16384 + seg*1024);
        }
#pragma unroll
        for (int u = 0; u < 2; u++) {            // V segs
            const int s2 = w + u*4;              // 0..7
            const int nt = s2 >> 1, kc = s2 & 1;
            const ushort* g = V + (size_t)(nt*16 + c)*NSEQ + kt*64 + kc*32 + quad*8;
            async16(g, smem + buf*16384 + 8192 + s2*1024);
        }
    };

    stage(0, 0);
    stage(1, 1);

    for (int kt = 0; kt < 16; kt++) {
        const int cur = kt % 3;
        if (kt < 15) {
            __asm__ volatile("s_waitcnt vmcnt(4)\n\ts_barrier" ::: "memory");
        } else {
            __asm__ volatile("s_waitcnt vmcnt(0)\n\ts_barrier" ::: "memory");
        }
        if (kt < 14) stage(kt + 2, (kt + 2) % 3);

        const char* Kb = smem + cur*16384;
        const char* Vb = smem + cur*16384 + 8192;

        f32x4 s[2][4];
#pragma unroll
        for (int nt = 0; nt < 4; nt++) {
            bf16x8 k0 = *(const bf16x8*)(Kb + (nt*2+0)*1024 + lane*16);
            bf16x8 k1 = *(const bf16x8*)(Kb + (nt*2+1)*1024 + lane*16);
#pragma unroll
            for (int m = 0; m < 2; m++) {
                f32x4 a = {0.f, 0.f, 0.f, 0.f};
                a = __builtin_amdgcn_mfma_f32_16x16x32_bf16(qf[m][0], k0, a, 0, 0, 0);
                a = __builtin_amdgcn_mfma_f32_16x16x32_bf16(qf[m][1], k1, a, 0, 0, 0);
                s[m][nt] = a;
            }
        }

#pragma unroll
        for (int m = 0; m < 2; m++) {
            ushort (*Psw)[72] = (ushort (*)[72])(smem + ATTN_P_OFF + (w*2+m)*2304);
#pragma unroll
            for (int nt = 0; nt < 4; nt++)
#pragma unroll
                for (int r = 0; r < 4; r++) {
                    const float p = exp2f(s[m][nt][r]);
                    lsum[m][r] += p;
                    Psw[quad*4 + r][nt*16 + c] = (ushort)__builtin_bit_cast(
                        unsigned short, (__bf16)p);
                }
        }
        __asm__ volatile("s_waitcnt lgkmcnt(0)" ::: "memory");

#pragma unroll
        for (int kc = 0; kc < 2; kc++) {
            bf16x8 vfr[4];
#pragma unroll
            for (int nt = 0; nt < 4; nt++)
                vfr[nt] = *(const bf16x8*)(Vb + (nt*2+kc)*1024 + lane*16);
#pragma unroll
            for (int m = 0; m < 2; m++) {
                ushort (*Psw)[72] = (ushort (*)[72])(smem + ATTN_P_OFF + (w*2+m)*2304);
                bf16x8 a = *(const bf16x8*)&Psw[c][kc*32 + quad*8];
#pragma unroll
                for (int nt = 0; nt < 4; nt++)
                    Oacc[m][nt] = __builtin_amdgcn_mfma_f32_16x16x32_bf16(
                        a, vfr[nt], Oacc[m][nt], 0, 0, 0);
            }
        }
        // no trailing barrier: buf cur is only overwritten by stage() issued
        // after the top-of-loop barrier two iterations from now; P region is
        // per-wave (same-wave DS ops complete in order)
    }

#pragma unroll
    for (int mk = 1; mk < 16; mk <<= 1)
#pragma unroll
        for (int m = 0; m < 2; m++)
#pragma unroll
            for (int r = 0; r < 4; r++)
                lsum[m][r] += __shfl_xor(lsum[m][r], mk);

    __syncthreads();
    float (*Osh)[68] = (float (*)[68])smem;   // [128][68]
    {
        float inv[2][4];
#pragma unroll
        for (int m = 0; m < 2; m++)
#pragma unroll
            for (int r = 0; r < 4; r++) inv[m][r] = 1.f / lsum[m][r];
#pragma unroll
        for (int m = 0; m < 2; m++)
#pragma unroll
            for (int nt = 0; nt < 4; nt++)
#pragma unroll
                for (int r = 0; r < 4; r++)
                    Osh[w*32 + m*16 + quad*4 + r][nt*16 + c] =
                        Oacc[m][nt][r] * inv[m][r];
    }
    __syncthreads();

#pragma unroll
    for (int u = 0; u < 8; u++) {
        const int t   = tid + u*256;       // 0..2047
        const int row = t >> 4;            // 0..127
        const int g   = t & 15;
        const int n   = qt*128 + row;
        const float o0 = Osh[row][g*4+0], o1 = Osh[row][g*4+1];
        const float o2 = Osh[row][g*4+2], o3 = Osh[row][g*4+3];
        const float* R = rot   + (size_t)(bb*NSEQ + n)*9;
        const float* T = trans + (size_t)(bb*NSEQ + n)*3;
        const float ti0 = -(R[0]*T[0] + R[3]*T[1] + R[6]*T[2]);
        const float ti1 = -(R[1]*T[0] + R[4]*T[1] + R[7]*T[2]);
        const float ti2 = -(R[2]*T[0] + R[5]*T[1] + R[8]*T[2]);
        const float p0 = R[0]*o0 + R[3]*o1 + R[6]*o2 + ti0*o3;
        const float p1 = R[1]*o0 + R[4]*o1 + R[7]*o2 + ti1*o3;
        const float p2 = R[2]*o0 + R[5]*o1 + R[8]*o2 + ti2*o3;
        const float p3 = o3;
        ushort4 hv = { f2bf(p0), f2bf(p1), f2bf(p2), f2bf(p3) };
        *(ushort4*)(om + (size_t)(bb*NSEQ + n)*INNER + h*DH + g*4) = hv;
    }
}

// ---------------------------------------------------------------------------
// Kernel 3: out^T single-pass bf16 MFMA GEMM: C = woT_bf16 * om_bf16.
// R14: QUAD-buffered LDS (4 x 16384 = 65536 B), ONE barrier per chunk,
// 3-chunk-deep DMA prefetch (grid is 1 block/CU -> all latency hiding must
// come from intra-block pipelining). Epilogue: + bias, fp32 store.
// ---------------------------------------------------------------------------
__global__ __launch_bounds__(256) void out_gemm_mfma(
    const ushort* __restrict__ Ag, const ushort* __restrict__ Bg,
    const float* __restrict__ bias, float* __restrict__ out)
{
    extern __shared__ __align__(16) char smem[];   // 65536 B

    const int tid  = threadIdx.x;
    const int lane = tid & 63;
    const int w    = tid >> 6;
    const int c    = lane & 15;
    const int quad = lane >> 4;
    const int wr   = w >> 1, wc = w & 1;
    const int tn   = blockIdx.x;   // token tile (64)
    const int tf   = blockIdx.y;   // feature tile (4)

    f32x4 acc[4][4] = {};

    // staging roles: part = w>>1 (0=A,1=B), group base = (w&1)*4
    const int part = w >> 1;
    const int g0   = (w & 1) * 4;
    const ushort* src = (part == 0) ? Ag : Bg;
    const ushort* wbase = src + (size_t)((part == 0 ? tf : tn)*128 + g0*16 + c)*INNER
                          + quad*8;

    auto stage = [&](int k0, int buf) {
#pragma unroll
        for (int g = 0; g < 4; g++)
            async16(wbase + (size_t)g*16*INNER + k0,
                    smem + buf*16384 + part*8192 + (g0 + g)*1024);
    };

    stage(0, 0);
    stage(32, 1);
    stage(64, 2);

    for (int ch = 0; ch < 16; ch++) {
        const int cur = ch & 3;
        // chunks in flight after the wait: min(3, 15-ch); 4 DMAs each
        if (ch < 14) {
            __asm__ volatile("s_waitcnt vmcnt(8)\n\ts_barrier" ::: "memory");
        } else if (ch == 14) {
            __asm__ volatile("s_waitcnt vmcnt(4)\n\ts_barrier" ::: "memory");
        } else {
            __asm__ volatile("s_waitcnt vmcnt(0)\n\ts_barrier" ::: "memory");
        }
        if (ch < 13) stage((ch+3)*32, (ch+3) & 3);

        const char* B = smem + cur*16384;
        bf16x8 fa[4], fb[4];
#pragma unroll
        for (int i = 0; i < 4; i++)
            fa[i] = *(const bf16x8*)(B + (wr*4 + i)*1024 + lane*16);
#pragma unroll
        for (int j = 0; j < 4; j++)
            fb[j] = *(const bf16x8*)(B + 8192 + (wc*4 + j)*1024 + lane*16);
#pragma unroll
        for (int i = 0; i < 4; i++)
#pragma unroll
            for (int j = 0; j < 4; j++)
                acc[i][j] = __builtin_amdgcn_mfma_f32_16x16x32_bf16(
                    fa[i], fb[j], acc[i][j], 0, 0, 0);
        // no trailing barrier (4-buffer rotation gates reuse via top barrier)
    }

#pragma unroll
    for (int j = 0; j < 4; j++) {
        const int tc = tn*128 + wc*64 + j*16 + c;
#pragma unroll
        for (int i = 0; i < 4; i++) {
            const int fr = tf*128 + wr*64 + i*16 + quad*4;
            float4 bv = *(const float4*)(bias + fr);
            float4 ov = { acc[i][j][0] + bv.x, acc[i][j][1] + bv.y,
                          acc[i][j][2] + bv.z, acc[i][j][3] + bv.w };
            *(float4*)(out + (size_t)tc*DIM + fr) = ov;
        }
    }
}

extern "C" void kernel_launch(void* const* d_in, const int* in_sizes, int n_in,
                              void* d_out, int out_size, void* d_ws, size_t ws_size,
                              hipStream_t stream) {
    (void)in_sizes; (void)n_in; (void)out_size; (void)ws_size;
    const float* x     = (const float*)d_in[0];
    const float* rot   = (const float*)d_in[1];
    const float* trans = (const float*)d_in[2];
    const float* w_qkv = (const float*)d_in[3];
    const float* b_qkv = (const float*)d_in[4];
    const float* w_out = (const float*)d_in[5];
    const float* b_out = (const float*)d_in[6];
    float* out = (float*)d_out;

    const size_t HB = (size_t)BSZ*NH*NSEQ*DH;        // 4,194,304 elements
    ushort* qb   = (ushort*)d_ws;
    ushort* kb   = qb   + HB;
    ushort* vt   = kb   + HB;                        // [BH][DH][NSEQ]
    ushort* woTh = vt   + HB;                        // [DIM][INNER]
    ushort* wqTh = woTh + (size_t)DIM*INNER;         // [QKVN][DIM]
    ushort* xh   = wqTh + (size_t)QKVN*DIM;          // [NTOK][DIM]
    ushort* xl   = xh   + HB;
    // om reuses xh (x consumed by kernel 1; om written by kernel 2)
    ushort* om   = xh;

    // dynamic-LDS opt-in for >64KB (and 64KB exactly) — host-side attribute
    // set, not a stream op; safe under graph capture. Idempotent.
    static int s_attr_done = 0;
    if (!s_attr_done) {
        (void)hipFuncSetAttribute((const void*)qkv_gemm_split,
            hipFuncAttributeMaxDynamicSharedMemorySize, 73728);
        (void)hipFuncSetAttribute((const void*)attn_mfma_kernel,
            hipFuncAttributeMaxDynamicSharedMemorySize, ATTN_LDS);
        (void)hipFuncSetAttribute((const void*)out_gemm_mfma,
            hipFuncAttributeMaxDynamicSharedMemorySize, 65536);
        s_attr_done = 1;
    }

    split_cvt_kernel<<<dim3(NTOK*DIM/1024), 256, 0, stream>>>(x, xh, xl);
    tconv_kernel<<<dim3(QKVN/32, DIM/32), 256, 0, stream>>>(w_qkv, wqTh, DIM, QKVN);
    tconv_kernel<<<dim3(DIM/32, INNER/32), 256, 0, stream>>>(w_out, woTh, INNER, DIM);

    qkv_gemm_split<<<dim3(NTOK/128, QKVN/128), 256, 73728, stream>>>(
        wqTh, xh, xl, b_qkv, rot, trans, qb, kb, vt);
    attn_mfma_kernel<<<dim3(NSEQ/128, BSZ*NH), 256, ATTN_LDS, stream>>>(
        qb, kb, vt, rot, trans, om);
    out_gemm_mfma<<<dim3(NTOK/128, DIM/128), 256, 65536, stream>>>(
        woTh, om, b_out, out);
}

// Round 2
// 178.905 us; speedup vs baseline: 1.0004x; 1.0004x over previous
//
#include <hip/hip_runtime.h>
#include <math.h>

#define BSZ   8
#define NSEQ  1024
#define DIM   512
#define NH    8
#define DH    64
#define INNER 512
#define NTOK  (BSZ*NSEQ)     // 8192
#define QKVN  (3*INNER)      // 1536

typedef __bf16 bf16x8 __attribute__((ext_vector_type(8)));
typedef float  f32x4  __attribute__((ext_vector_type(4)));

// q pre-scale: softmax scale (DH^-0.5 = 0.125) folded with log2(e)
#define QSCL (0.125f * 1.44269504088896f)

// attn LDS layout: 3 K/V buffers of 16384, then P region
#define ATTN_P_OFF 49152
#define ATTN_LDS   67584

static __device__ __forceinline__ ushort f2bf(float f) {
    union { float f; unsigned u; } v; v.f = f;
    unsigned r = (v.u + 0x7FFFu + ((v.u >> 16) & 1u)) >> 16;  // RNE
    return (ushort)r;
}
static __device__ __forceinline__ float bf2f(ushort u) {
    union { unsigned u; float f; } v; v.u = ((unsigned)u) << 16;
    return v.f;
}
static __device__ __forceinline__ void split2(float x, ushort& h, ushort& l) {
    h = f2bf(x);
    l = f2bf(x - bf2f(h));
}
// async global->LDS DMA, 16B per lane; LDS dest = wave-uniform base + lane*16
static __device__ __forceinline__ void async16(const void* g, void* l) {
    __builtin_amdgcn_global_load_lds(
        (const __attribute__((address_space(1))) unsigned int*)g,
        (__attribute__((address_space(3))) unsigned int*)l, 16, 0, 0);
}

// ---------------------------------------------------------------------------
// Elementwise fp32 -> bf16 hi/lo split (x)
// ---------------------------------------------------------------------------
__global__ __launch_bounds__(256) void split_cvt_kernel(
    const float* __restrict__ in, ushort* __restrict__ oh, ushort* __restrict__ ol)
{
    const int i = blockIdx.x * 256 + threadIdx.x;
    float4 v = ((const float4*)in)[i];
    ushort4 h, l;
    split2(v.x, h.x, l.x); split2(v.y, h.y, l.y);
    split2(v.z, h.z, l.z); split2(v.w, h.w, l.w);
    ((ushort4*)oh)[i] = h;
    ((ushort4*)ol)[i] = l;
}

// ---------------------------------------------------------------------------
// Transpose + convert: in [K][F] fp32 row-major -> out [F][K] bf16
// ---------------------------------------------------------------------------
__global__ __launch_bounds__(256) void tconv_kernel(
    const float* __restrict__ in, ushort* __restrict__ outh, int K, int F)
{
    __shared__ float tile[32][33];
    const int bx = blockIdx.x;           // F/32
    const int by = blockIdx.y;           // K/32
    const int lx = threadIdx.x & 31, ly = threadIdx.x >> 5;
#pragma unroll
    for (int u = 0; u < 4; u++) {
        const int k = by*32 + ly + u*8;
        tile[ly + u*8][lx] = in[(size_t)k*F + bx*32 + lx];
    }
    __syncthreads();
#pragma unroll
    for (int u = 0; u < 4; u++) {
        const int f = bx*32 + ly + u*8;
        outh[(size_t)f*K + by*32 + lx] = f2bf(tile[lx][ly + u*8]);
    }
}

// ---------------------------------------------------------------------------
// Kernel 1: qkv^T MFMA GEMM: C = w_bf16 * (xh + xl), 2 passes, 3 staged
// parts (Ah/Bh/Bl), BK=32, fine-grained vmcnt pipeline (R11, proven).
// R15: reverted to R11 double-buffer structure — the R14 triple-buffer cost
// a resident block (3->2 blocks/CU at 73728 B LDS) and regressed 47->67 us;
// inter-block overlap beats intra-block pipeline depth for this kernel.
// Epilogue: bias + SE(3) pose; q,k row-major; V written transposed to vt.
// ---------------------------------------------------------------------------
__global__ __launch_bounds__(256) void qkv_gemm_split(
    const ushort* __restrict__ Agh, const ushort* __restrict__ Bgh,
    const ushort* __restrict__ Bgl,
    const float* __restrict__ bias, const float* __restrict__ rot,
    const float* __restrict__ trans,
    ushort* __restrict__ qb, ushort* __restrict__ kb, ushort* __restrict__ vt)
{
    extern __shared__ __align__(16) char smem[];   // 49152 B

    const int tid  = threadIdx.x;
    const int lane = tid & 63;
    const int w    = tid >> 6;
    const int c    = lane & 15;
    const int quad = lane >> 4;
    const int wr   = w >> 1, wc = w & 1;
    const int tn   = blockIdx.x;   // token tile (64)
    const int tf   = blockIdx.y;   // feature tile (12)

    f32x4 acc[4][4] = {};

    // wave roles: 0 -> Ah, 1 -> Bh, 2 -> Bl, 3 -> idle (issue-only staging)
    const ushort* wp = (w == 0) ? Agh : (w == 1) ? Bgh : Bgl;
    const ushort* wbase = wp + (size_t)((w == 0 ? tf : tn)*128 + c)*DIM + quad*8;
    const int lbase = w * 8192;    // A at 0, Bh at 8192, Bl at 16384

    auto stage = [&](int k0, int buf) {
        if (w < 3) {
#pragma unroll
            for (int g = 0; g < 8; g++)
                async16(wbase + (size_t)g*16*DIM + k0,
                        smem + buf*24576 + lbase + g*1024);
        }
    };

    stage(0, 0);

    for (int ch = 0; ch < 16; ch++) {
        const int cur = ch & 1, nxt = cur ^ 1;
        if (ch < 15) {
            stage((ch+1)*32, nxt);
            // wait only chunk-ch's 8 DMAs (oldest); ch+1's stay in flight
            __asm__ volatile("s_waitcnt vmcnt(8)\n\ts_barrier" ::: "memory");
        } else {
            __asm__ volatile("s_waitcnt vmcnt(0)\n\ts_barrier" ::: "memory");
        }

        const char* B = smem + cur*24576;
        bf16x8 fa[4], fbh[4], fbl[4];
#pragma unroll
        for (int i = 0; i < 4; i++)
            fa[i] = *(const bf16x8*)(B + (wr*4 + i)*1024 + lane*16);
#pragma unroll
        for (int j = 0; j < 4; j++) {
            fbh[j] = *(const bf16x8*)(B +  8192 + (wc*4 + j)*1024 + lane*16);
            fbl[j] = *(const bf16x8*)(B + 16384 + (wc*4 + j)*1024 + lane*16);
        }
#pragma unroll
        for (int i = 0; i < 4; i++)
#pragma unroll
            for (int j = 0; j < 4; j++) {
                acc[i][j] = __builtin_amdgcn_mfma_f32_16x16x32_bf16(
                    fa[i], fbh[j], acc[i][j], 0, 0, 0);
                acc[i][j] = __builtin_amdgcn_mfma_f32_16x16x32_bf16(
                    fa[i], fbl[j], acc[i][j], 0, 0, 0);
            }
        __asm__ volatile("s_waitcnt lgkmcnt(0)\n\ts_barrier" ::: "memory");
    }

    // epilogue: bias + SE(3) pose + scatter (verified mapping)
    const int sec = tf >> 2;          // 0=q 1=k 2=v (block-uniform)

#pragma unroll
    for (int j = 0; j < 4; j++) {
        const int tc = tn*128 + wc*64 + j*16 + c;
        const int bb = tc >> 10, n = tc & 1023;
        const float* R = rot   + (size_t)(bb*NSEQ + n)*9;
        const float* T = trans + (size_t)(bb*NSEQ + n)*3;
        const float R0=R[0],R1=R[1],R2=R[2],R3=R[3],R4=R[4],R5=R[5],R6=R[6],R7=R[7],R8=R[8];
        const float T0=T[0],T1=T[1],T2=T[2];
        float ti0 = 0.f, ti1 = 0.f, ti2 = 0.f;
        if (sec == 0) {
            ti0 = -(R0*T0 + R3*T1 + R6*T2);
            ti1 = -(R1*T0 + R4*T1 + R7*T2);
            ti2 = -(R2*T0 + R5*T1 + R8*T2);
        }
#pragma unroll
        for (int i = 0; i < 4; i++) {
            const int fr = tf*128 + wr*64 + i*16 + quad*4;
            const int fl = fr & 511;
            const int h  = fl >> 6, d = fl & 63;
            float4 bv = *(const float4*)(bias + fr);
            const float g0 = acc[i][j][0] + bv.x;
            const float g1 = acc[i][j][1] + bv.y;
            const float g2 = acc[i][j][2] + bv.z;
            const float g3 = acc[i][j][3] + bv.w;
            if (sec == 0) {
                float o0 = (R0*g0 + R1*g1 + R2*g2) * QSCL;
                float o1 = (R3*g0 + R4*g1 + R5*g2) * QSCL;
                float o2 = (R6*g0 + R7*g1 + R8*g2) * QSCL;
                float o3 = (ti0*g0 + ti1*g1 + ti2*g2 + g3) * QSCL;
                ushort4 ov = { f2bf(o0), f2bf(o1), f2bf(o2), f2bf(o3) };
                *(ushort4*)(qb + ((size_t)((bb*NH + h)*NSEQ + n))*DH + d) = ov;
            } else {
                float o0 = R0*g0 + R1*g1 + R2*g2 + T0*g3;
                float o1 = R3*g0 + R4*g1 + R5*g2 + T1*g3;
                float o2 = R6*g0 + R7*g1 + R8*g2 + T2*g3;
                float o3 = g3;
                if (sec == 1) {
                    ushort4 ov = { f2bf(o0), f2bf(o1), f2bf(o2), f2bf(o3) };
                    *(ushort4*)(kb + ((size_t)((bb*NH + h)*NSEQ + n))*DH + d) = ov;
                } else {
                    // v: write TRANSPOSED -> vt[bh][d][n]
                    ushort* vtb = vt + ((size_t)(bb*NH + h)*DH + d)*NSEQ + n;
                    vtb[0*NSEQ] = f2bf(o0);
                    vtb[1*NSEQ] = f2bf(o1);
                    vtb[2*NSEQ] = f2bf(o2);
                    vtb[3*NSEQ] = f2bf(o3);
                }
            }
        }
    }
}

// ---------------------------------------------------------------------------
// Kernel 2: async-pipelined MFMA flash attention.
// R14 (kept): TRIPLE-buffered K/V LDS (3 x 16384), ONE barrier per kt, 2-deep
// prefetch. P region at +49152 (per-wave, no cross-wave hazard).
// Dynamic LDS = 67584 B (2 blocks/CU — matches grid of 2 blocks/CU, so the
// extra buffer costs no residency here, unlike qkv).
// ---------------------------------------------------------------------------
__global__ __launch_bounds__(256) void attn_mfma_kernel(
    const ushort* __restrict__ qb, const ushort* __restrict__ kb,
    const ushort* __restrict__ vt, const float* __restrict__ rot,
    const float* __restrict__ trans, ushort* __restrict__ om)
{
    extern __shared__ __align__(16) char smem[];   // 67584 B

    const int tid  = threadIdx.x;
    const int lane = tid & 63;
    const int w    = tid >> 6;
    const int c    = lane & 15;
    const int quad = lane >> 4;

    const int qt = blockIdx.x;      // 0..7 (128 q rows)
    const int bh = blockIdx.y;      // 0..63
    const int bb = bh >> 3, h = bh & 7;

    const ushort* Q = qb + (size_t)bh * NSEQ * DH;
    const ushort* K = kb + (size_t)bh * NSEQ * DH;
    const ushort* V = vt + (size_t)bh * DH * NSEQ;   // [DH][NSEQ]

    bf16x8 qf[2][2];
#pragma unroll
    for (int m = 0; m < 2; m++) {
        const ushort* qrow = Q + (size_t)(qt*128 + w*32 + m*16 + c)*DH + quad*8;
        qf[m][0] = *(const bf16x8*)(qrow);
        qf[m][1] = *(const bf16x8*)(qrow + 32);
    }

    f32x4 Oacc[2][4] = {};
    float lsum[2][4] = {};

    auto stage = [&](int kt, int buf) {
#pragma unroll
        for (int u = 0; u < 2; u++) {            // K segs
            const int seg = w + u*4;             // 0..7
            const int nt = seg >> 1, hh = seg & 1;
            const ushort* g = K + (size_t)(kt*64 + nt*16 + c)*DH + hh*32 + quad*8;
            async16(g, smem + buf*16384 + seg*1024);
        }
#pragma unroll
        for (int u = 0; u < 2; u++) {            // V segs
            const int s2 = w + u*4;              // 0..7
            const int nt = s2 >> 1, kc = s2 & 1;
            const ushort* g = V + (size_t)(nt*16 + c)*NSEQ + kt*64 + kc*32 + quad*8;
            async16(g, smem + buf*16384 + 8192 + s2*1024);
        }
    };

    stage(0, 0);
    stage(1, 1);

    for (int kt = 0; kt < 16; kt++) {
        const int cur = kt % 3;
        if (kt < 15) {
            __asm__ volatile("s_waitcnt vmcnt(4)\n\ts_barrier" ::: "memory");
        } else {
            __asm__ volatile("s_waitcnt vmcnt(0)\n\ts_barrier" ::: "memory");
        }
        if (kt < 14) stage(kt + 2, (kt + 2) % 3);

        const char* Kb = smem + cur*16384;
        const char* Vb = smem + cur*16384 + 8192;

        f32x4 s[2][4];
#pragma unroll
        for (int nt = 0; nt < 4; nt++) {
            bf16x8 k0 = *(const bf16x8*)(Kb + (nt*2+0)*1024 + lane*16);
            bf16x8 k1 = *(const bf16x8*)(Kb + (nt*2+1)*1024 + lane*16);
#pragma unroll
            for (int m = 0; m < 2; m++) {
                f32x4 a = {0.f, 0.f, 0.f, 0.f};
                a = __builtin_amdgcn_mfma_f32_16x16x32_bf16(qf[m][0], k0, a, 0, 0, 0);
                a = __builtin_amdgcn_mfma_f32_16x16x32_bf16(qf[m][1], k1, a, 0, 0, 0);
                s[m][nt] = a;
            }
        }

#pragma unroll
        for (int m = 0; m < 2; m++) {
            ushort (*Psw)[72] = (ushort (*)[72])(smem + ATTN_P_OFF + (w*2+m)*2304);
#pragma unroll
            for (int nt = 0; nt < 4; nt++)
#pragma unroll
                for (int r = 0; r < 4; r++) {
                    const float p = exp2f(s[m][nt][r]);
                    lsum[m][r] += p;
                    Psw[quad*4 + r][nt*16 + c] = (ushort)__builtin_bit_cast(
                        unsigned short, (__bf16)p);
                }
        }
        __asm__ volatile("s_waitcnt lgkmcnt(0)" ::: "memory");

#pragma unroll
        for (int kc = 0; kc < 2; kc++) {
            bf16x8 vfr[4];
#pragma unroll
            for (int nt = 0; nt < 4; nt++)
                vfr[nt] = *(const bf16x8*)(Vb + (nt*2+kc)*1024 + lane*16);
#pragma unroll
            for (int m = 0; m < 2; m++) {
                ushort (*Psw)[72] = (ushort (*)[72])(smem + ATTN_P_OFF + (w*2+m)*2304);
                bf16x8 a = *(const bf16x8*)&Psw[c][kc*32 + quad*8];
#pragma unroll
                for (int nt = 0; nt < 4; nt++)
                    Oacc[m][nt] = __builtin_amdgcn_mfma_f32_16x16x32_bf16(
                        a, vfr[nt], Oacc[m][nt], 0, 0, 0);
            }
        }
        // no trailing barrier: buf cur is only overwritten by stage() issued
        // after the top-of-loop barrier two iterations from now; P region is
        // per-wave (same-wave DS ops complete in order)
    }

#pragma unroll
    for (int mk = 1; mk < 16; mk <<= 1)
#pragma unroll
        for (int m = 0; m < 2; m++)
#pragma unroll
            for (int r = 0; r < 4; r++)
                lsum[m][r] += __shfl_xor(lsum[m][r], mk);

    __syncthreads();
    float (*Osh)[68] = (float (*)[68])smem;   // [128][68]
    {
        float inv[2][4];
#pragma unroll
        for (int m = 0; m < 2; m++)
#pragma unroll
            for (int r = 0; r < 4; r++) inv[m][r] = 1.f / lsum[m][r];
#pragma unroll
        for (int m = 0; m < 2; m++)
#pragma unroll
            for (int nt = 0; nt < 4; nt++)
#pragma unroll
                for (int r = 0; r < 4; r++)
                    Osh[w*32 + m*16 + quad*4 + r][nt*16 + c] =
                        Oacc[m][nt][r] * inv[m][r];
    }
    __syncthreads();

#pragma unroll
    for (int u = 0; u < 8; u++) {
        const int t   = tid + u*256;       // 0..2047
        const int row = t >> 4;            // 0..127
        const int g   = t & 15;
        const int n   = qt*128 + row;
        const float o0 = Osh[row][g*4+0], o1 = Osh[row][g*4+1];
        const float o2 = Osh[row][g*4+2], o3 = Osh[row][g*4+3];
        const float* R = rot   + (size_t)(bb*NSEQ + n)*9;
        const float* T = trans + (size_t)(bb*NSEQ + n)*3;
        const float ti0 = -(R[0]*T[0] + R[3]*T[1] + R[6]*T[2]);
        const float ti1 = -(R[1]*T[0] + R[4]*T[1] + R[7]*T[2]);
        const float ti2 = -(R[2]*T[0] + R[5]*T[1] + R[8]*T[2]);
        const float p0 = R[0]*o0 + R[3]*o1 + R[6]*o2 + ti0*o3;
        const float p1 = R[1]*o0 + R[4]*o1 + R[7]*o2 + ti1*o3;
        const float p2 = R[2]*o0 + R[5]*o1 + R[8]*o2 + ti2*o3;
        const float p3 = o3;
        ushort4 hv = { f2bf(p0), f2bf(p1), f2bf(p2), f2bf(p3) };
        *(ushort4*)(om + (size_t)(bb*NSEQ + n)*INNER + h*DH + g*4) = hv;
    }
}

// ---------------------------------------------------------------------------
// Kernel 3: out^T single-pass bf16 MFMA GEMM: C = woT_bf16 * om_bf16.
// R14 (kept): QUAD-buffered LDS (4 x 16384 = 65536 B), ONE barrier per chunk,
// 3-chunk-deep DMA prefetch (grid is 1 block/CU -> all latency hiding must
// come from intra-block pipelining; extra LDS costs no residency).
// Epilogue: + bias, fp32 store.
// ---------------------------------------------------------------------------
__global__ __launch_bounds__(256) void out_gemm_mfma(
    const ushort* __restrict__ Ag, const ushort* __restrict__ Bg,
    const float* __restrict__ bias, float* __restrict__ out)
{
    extern __shared__ __align__(16) char smem[];   // 65536 B

    const int tid  = threadIdx.x;
    const int lane = tid & 63;
    const int w    = tid >> 6;
    const int c    = lane & 15;
    const int quad = lane >> 4;
    const int wr   = w >> 1, wc = w & 1;
    const int tn   = blockIdx.x;   // token tile (64)
    const int tf   = blockIdx.y;   // feature tile (4)

    f32x4 acc[4][4] = {};

    // staging roles: part = w>>1 (0=A,1=B), group base = (w&1)*4
    const int part = w >> 1;
    const int g0   = (w & 1) * 4;
    const ushort* src = (part == 0) ? Ag : Bg;
    const ushort* wbase = src + (size_t)((part == 0 ? tf : tn)*128 + g0*16 + c)*INNER
                          + quad*8;

    auto stage = [&](int k0, int buf) {
#pragma unroll
        for (int g = 0; g < 4; g++)
            async16(wbase + (size_t)g*16*INNER + k0,
                    smem + buf*16384 + part*8192 + (g0 + g)*1024);
    };

    stage(0, 0);
    stage(32, 1);
    stage(64, 2);

    for (int ch = 0; ch < 16; ch++) {
        const int cur = ch & 3;
        // chunks in flight after the wait: min(3, 15-ch); 4 DMAs each
        if (ch < 14) {
            __asm__ volatile("s_waitcnt vmcnt(8)\n\ts_barrier" ::: "memory");
        } else if (ch == 14) {
            __asm__ volatile("s_waitcnt vmcnt(4)\n\ts_barrier" ::: "memory");
        } else {
            __asm__ volatile("s_waitcnt vmcnt(0)\n\ts_barrier" ::: "memory");
        }
        if (ch < 13) stage((ch+3)*32, (ch+3) & 3);

        const char* B = smem + cur*16384;
        bf16x8 fa[4], fb[4];
#pragma unroll
        for (int i = 0; i < 4; i++)
            fa[i] = *(const bf16x8*)(B + (wr*4 + i)*1024 + lane*16);
#pragma unroll
        for (int j = 0; j < 4; j++)
            fb[j] = *(const bf16x8*)(B + 8192 + (wc*4 + j)*1024 + lane*16);
#pragma unroll
        for (int i = 0; i < 4; i++)
#pragma unroll
            for (int j = 0; j < 4; j++)
                acc[i][j] = __builtin_amdgcn_mfma_f32_16x16x32_bf16(
                    fa[i], fb[j], acc[i][j], 0, 0, 0);
        // no trailing barrier (4-buffer rotation gates reuse via top barrier)
    }

#pragma unroll
    for (int j = 0; j < 4; j++) {
        const int tc = tn*128 + wc*64 + j*16 + c;
#pragma unroll
        for (int i = 0; i < 4; i++) {
            const int fr = tf*128 + wr*64 + i*16 + quad*4;
            float4 bv = *(const float4*)(bias + fr);
            float4 ov = { acc[i][j][0] + bv.x, acc[i][j][1] + bv.y,
                          acc[i][j][2] + bv.z, acc[i][j][3] + bv.w };
            *(float4*)(out + (size_t)tc*DIM + fr) = ov;
        }
    }
}

extern "C" void kernel_launch(void* const* d_in, const int* in_sizes, int n_in,
                              void* d_out, int out_size, void* d_ws, size_t ws_size,
                              hipStream_t stream) {
    (void)in_sizes; (void)n_in; (void)out_size; (void)ws_size;
    const float* x     = (const float*)d_in[0];
    const float* rot   = (const float*)d_in[1];
    const float* trans = (const float*)d_in[2];
    const float* w_qkv = (const float*)d_in[3];
    const float* b_qkv = (const float*)d_in[4];
    const float* w_out = (const float*)d_in[5];
    const float* b_out = (const float*)d_in[6];
    float* out = (float*)d_out;

    const size_t HB = (size_t)BSZ*NH*NSEQ*DH;        // 4,194,304 elements
    ushort* qb   = (ushort*)d_ws;
    ushort* kb   = qb   + HB;
    ushort* vt   = kb   + HB;                        // [BH][DH][NSEQ]
    ushort* woTh = vt   + HB;                        // [DIM][INNER]
    ushort* wqTh = woTh + (size_t)DIM*INNER;         // [QKVN][DIM]
    ushort* xh   = wqTh + (size_t)QKVN*DIM;          // [NTOK][DIM]
    ushort* xl   = xh   + HB;
    // om reuses xh (x consumed by kernel 1; om written by kernel 2)
    ushort* om   = xh;

    // dynamic-LDS opt-in for >=64KB — host-side attribute set, not a stream
    // op; safe under graph capture. Idempotent.
    static int s_attr_done = 0;
    if (!s_attr_done) {
        (void)hipFuncSetAttribute((const void*)attn_mfma_kernel,
            hipFuncAttributeMaxDynamicSharedMemorySize, ATTN_LDS);
        (void)hipFuncSetAttribute((const void*)out_gemm_mfma,
            hipFuncAttributeMaxDynamicSharedMemorySize, 65536);
        s_attr_done = 1;
    }

    split_cvt_kernel<<<dim3(NTOK*DIM/1024), 256, 0, stream>>>(x, xh, xl);
    tconv_kernel<<<dim3(QKVN/32, DIM/32), 256, 0, stream>>>(w_qkv, wqTh, DIM, QKVN);
    tconv_kernel<<<dim3(DIM/32, INNER/32), 256, 0, stream>>>(w_out, woTh, INNER, DIM);

    qkv_gemm_split<<<dim3(NTOK/128, QKVN/128), 256, 49152, stream>>>(
        wqTh, xh, xl, b_qkv, rot, trans, qb, kb, vt);
    attn_mfma_kernel<<<dim3(NSEQ/128, BSZ*NH), 256, ATTN_LDS, stream>>>(
        qb, kb, vt, rot, trans, om);
    out_gemm_mfma<<<dim3(NTOK/128, DIM/128), 256, 65536, stream>>>(
        woTh, om, b_out, out);
}

// Round 3
// 164.711 us; speedup vs baseline: 1.0866x; 1.0862x over previous
//
#include <hip/hip_runtime.h>
#include <math.h>

#define BSZ   8
#define NSEQ  1024
#define DIM   512
#define NH    8
#define DH    64
#define INNER 512
#define NTOK  (BSZ*NSEQ)     // 8192
#define QKVN  (3*INNER)      // 1536

typedef __bf16   bf16x8 __attribute__((ext_vector_type(8)));
typedef _Float16 f16x8  __attribute__((ext_vector_type(8)));
typedef float    f32x4  __attribute__((ext_vector_type(4)));

// q pre-scale: softmax scale (DH^-0.5 = 0.125) folded with log2(e)
#define QSCL (0.125f * 1.44269504088896f)

// attn LDS layout: 3 K/V buffers of 16384, then P region
#define ATTN_P_OFF 49152
#define ATTN_LDS   67584

static __device__ __forceinline__ ushort f2bf(float f) {
    union { float f; unsigned u; } v; v.f = f;
    unsigned r = (v.u + 0x7FFFu + ((v.u >> 16) & 1u)) >> 16;  // RNE
    return (ushort)r;
}
static __device__ __forceinline__ ushort f2h(float f) {
    _Float16 h = (_Float16)f;                                  // RNE
    return __builtin_bit_cast(unsigned short, h);
}
// async global->LDS DMA, 16B per lane; LDS dest = wave-uniform base + lane*16
static __device__ __forceinline__ void async16(const void* g, void* l) {
    __builtin_amdgcn_global_load_lds(
        (const __attribute__((address_space(1))) unsigned int*)g,
        (__attribute__((address_space(3))) unsigned int*)l, 16, 0, 0);
}

// ---------------------------------------------------------------------------
// Fused prep kernel (R16): one dispatch replaces split_cvt + 2x tconv.
//   blocks [0,4096):    x fp32 -> fp16 (single array; hi/lo split dropped)
//   blocks [4096,4864): w_qkv [DIM][QKVN] -> wqT fp16 [QKVN][DIM]
//   blocks [4864,5120): w_out [INNER][DIM] -> woT bf16 [DIM][INNER]
// ---------------------------------------------------------------------------
__global__ __launch_bounds__(256) void prep_kernel(
    const float* __restrict__ x,  ushort* __restrict__ xf,
    const float* __restrict__ wq, ushort* __restrict__ wqT,
    const float* __restrict__ wo, ushort* __restrict__ woT)
{
    const int bid = blockIdx.x;
    if (bid < 4096) {
        const int i = bid*256 + threadIdx.x;
        float4 v = ((const float4*)x)[i];
        ushort4 h = { f2h(v.x), f2h(v.y), f2h(v.z), f2h(v.w) };
        ((ushort4*)xf)[i] = h;
        return;
    }
    __shared__ float tile[32][33];
    int K, F, bx, by; const float* in; ushort* outp; int is_q;
    if (bid < 4096 + 768) {
        const int id = bid - 4096;
        bx = id % 48; by = id / 48;          // F/32=48, K/32=16
        K = DIM; F = QKVN; in = wq; outp = wqT; is_q = 1;
    } else {
        const int id = bid - 4864;
        bx = id % 16; by = id / 16;          // F/32=16, K/32=16
        K = INNER; F = DIM; in = wo; outp = woT; is_q = 0;
    }
    const int lx = threadIdx.x & 31, ly = threadIdx.x >> 5;
#pragma unroll
    for (int u = 0; u < 4; u++) {
        const int k = by*32 + ly + u*8;
        tile[ly + u*8][lx] = in[(size_t)k*F + bx*32 + lx];
    }
    __syncthreads();
#pragma unroll
    for (int u = 0; u < 4; u++) {
        const int f = bx*32 + ly + u*8;
        const float v = tile[lx][ly + u*8];
        outp[(size_t)f*K + by*32 + lx] = is_q ? f2h(v) : f2bf(v);
    }
}

// ---------------------------------------------------------------------------
// Kernel 1 (R16): qkv^T MFMA GEMM in fp16 SINGLE PASS: C = wqT_f16 * x_f16.
// Rationale: output is rounded to bf16 on store anyway (error floor 2^-9);
// fp16 inputs (2^-11 each) are MORE accurate than the old bf16-W x (hi/lo-x)
// scheme while halving MFMA work and staging bytes. Structure = proven R11:
// double-buffered LDS (2 x 16384 = 32768 B), BK=32, stage-before-wait,
// per-wave vmcnt(4) (all 4 waves stage 4 DMAs each, out_gemm pattern),
// trailing lgkmcnt(0)+barrier. Epilogue: bias + SE(3) pose, unchanged.
// ---------------------------------------------------------------------------
__global__ __launch_bounds__(256) void qkv_gemm_f16(
    const ushort* __restrict__ Ag,   // wqT fp16 [QKVN][DIM]
    const ushort* __restrict__ Bg,   // x   fp16 [NTOK][DIM]
    const float* __restrict__ bias, const float* __restrict__ rot,
    const float* __restrict__ trans,
    ushort* __restrict__ qb, ushort* __restrict__ kb, ushort* __restrict__ vt)
{
    extern __shared__ __align__(16) char smem[];   // 32768 B

    const int tid  = threadIdx.x;
    const int lane = tid & 63;
    const int w    = tid >> 6;
    const int c    = lane & 15;
    const int quad = lane >> 4;
    const int wr   = w >> 1, wc = w & 1;
    const int tn   = blockIdx.x;   // token tile (64)
    const int tf   = blockIdx.y;   // feature tile (12)

    f32x4 acc[4][4] = {};

    // staging roles: part = w>>1 (0=A,1=B), group base = (w&1)*4
    const int part = w >> 1;
    const int g0   = (w & 1) * 4;
    const ushort* src = (part == 0) ? Ag : Bg;
    const ushort* wbase = src + (size_t)((part == 0 ? tf : tn)*128 + g0*16 + c)*DIM
                          + quad*8;

    auto stage = [&](int k0, int buf) {
#pragma unroll
        for (int g = 0; g < 4; g++)
            async16(wbase + (size_t)g*16*DIM + k0,
                    smem + buf*16384 + part*8192 + (g0 + g)*1024);
    };

    stage(0, 0);

    for (int ch = 0; ch < 16; ch++) {
        const int cur = ch & 1, nxt = cur ^ 1;
        if (ch < 15) {
            stage((ch+1)*32, nxt);
            // wait own chunk-ch's 4 DMAs (oldest); ch+1's 4 stay in flight
            __asm__ volatile("s_waitcnt vmcnt(4)\n\ts_barrier" ::: "memory");
        } else {
            __asm__ volatile("s_waitcnt vmcnt(0)\n\ts_barrier" ::: "memory");
        }

        const char* B = smem + cur*16384;
        f16x8 fa[4], fb[4];
#pragma unroll
        for (int i = 0; i < 4; i++)
            fa[i] = *(const f16x8*)(B + (wr*4 + i)*1024 + lane*16);
#pragma unroll
        for (int j = 0; j < 4; j++)
            fb[j] = *(const f16x8*)(B + 8192 + (wc*4 + j)*1024 + lane*16);
#pragma unroll
        for (int i = 0; i < 4; i++)
#pragma unroll
            for (int j = 0; j < 4; j++)
                acc[i][j] = __builtin_amdgcn_mfma_f32_16x16x32_f16(
                    fa[i], fb[j], acc[i][j], 0, 0, 0);
        __asm__ volatile("s_waitcnt lgkmcnt(0)\n\ts_barrier" ::: "memory");
    }

    // epilogue: bias + SE(3) pose + scatter (verified mapping, unchanged)
    const int sec = tf >> 2;          // 0=q 1=k 2=v (block-uniform)

#pragma unroll
    for (int j = 0; j < 4; j++) {
        const int tc = tn*128 + wc*64 + j*16 + c;
        const int bb = tc >> 10, n = tc & 1023;
        const float* R = rot   + (size_t)(bb*NSEQ + n)*9;
        const float* T = trans + (size_t)(bb*NSEQ + n)*3;
        const float R0=R[0],R1=R[1],R2=R[2],R3=R[3],R4=R[4],R5=R[5],R6=R[6],R7=R[7],R8=R[8];
        const float T0=T[0],T1=T[1],T2=T[2];
        float ti0 = 0.f, ti1 = 0.f, ti2 = 0.f;
        if (sec == 0) {
            ti0 = -(R0*T0 + R3*T1 + R6*T2);
            ti1 = -(R1*T0 + R4*T1 + R7*T2);
            ti2 = -(R2*T0 + R5*T1 + R8*T2);
        }
#pragma unroll
        for (int i = 0; i < 4; i++) {
            const int fr = tf*128 + wr*64 + i*16 + quad*4;
            const int fl = fr & 511;
            const int h  = fl >> 6, d = fl & 63;
            float4 bv = *(const float4*)(bias + fr);
            const float g0v = acc[i][j][0] + bv.x;
            const float g1v = acc[i][j][1] + bv.y;
            const float g2v = acc[i][j][2] + bv.z;
            const float g3v = acc[i][j][3] + bv.w;
            if (sec == 0) {
                float o0 = (R0*g0v + R1*g1v + R2*g2v) * QSCL;
                float o1 = (R3*g0v + R4*g1v + R5*g2v) * QSCL;
                float o2 = (R6*g0v + R7*g1v + R8*g2v) * QSCL;
                float o3 = (ti0*g0v + ti1*g1v + ti2*g2v + g3v) * QSCL;
                ushort4 ov = { f2bf(o0), f2bf(o1), f2bf(o2), f2bf(o3) };
                *(ushort4*)(qb + ((size_t)((bb*NH + h)*NSEQ + n))*DH + d) = ov;
            } else {
                float o0 = R0*g0v + R1*g1v + R2*g2v + T0*g3v;
                float o1 = R3*g0v + R4*g1v + R5*g2v + T1*g3v;
                float o2 = R6*g0v + R7*g1v + R8*g2v + T2*g3v;
                float o3 = g3v;
                if (sec == 1) {
                    ushort4 ov = { f2bf(o0), f2bf(o1), f2bf(o2), f2bf(o3) };
                    *(ushort4*)(kb + ((size_t)((bb*NH + h)*NSEQ + n))*DH + d) = ov;
                } else {
                    // v: write TRANSPOSED -> vt[bh][d][n]
                    ushort* vtb = vt + ((size_t)(bb*NH + h)*DH + d)*NSEQ + n;
                    vtb[0*NSEQ] = f2bf(o0);
                    vtb[1*NSEQ] = f2bf(o1);
                    vtb[2*NSEQ] = f2bf(o2);
                    vtb[3*NSEQ] = f2bf(o3);
                }
            }
        }
    }
}

// ---------------------------------------------------------------------------
// Kernel 2: async-pipelined MFMA flash attention.
// (kept from R14/R15, passing twice): TRIPLE-buffered K/V LDS (3 x 16384),
// ONE barrier per kt, 2-deep prefetch. P region at +49152 (per-wave).
// Dynamic LDS = 67584 B (2 blocks/CU — matches grid of 2 blocks/CU).
// ---------------------------------------------------------------------------
__global__ __launch_bounds__(256) void attn_mfma_kernel(
    const ushort* __restrict__ qb, const ushort* __restrict__ kb,
    const ushort* __restrict__ vt, const float* __restrict__ rot,
    const float* __restrict__ trans, ushort* __restrict__ om)
{
    extern __shared__ __align__(16) char smem[];   // 67584 B

    const int tid  = threadIdx.x;
    const int lane = tid & 63;
    const int w    = tid >> 6;
    const int c    = lane & 15;
    const int quad = lane >> 4;

    const int qt = blockIdx.x;      // 0..7 (128 q rows)
    const int bh = blockIdx.y;      // 0..63
    const int bb = bh >> 3, h = bh & 7;

    const ushort* Q = qb + (size_t)bh * NSEQ * DH;
    const ushort* K = kb + (size_t)bh * NSEQ * DH;
    const ushort* V = vt + (size_t)bh * DH * NSEQ;   // [DH][NSEQ]

    bf16x8 qf[2][2];
#pragma unroll
    for (int m = 0; m < 2; m++) {
        const ushort* qrow = Q + (size_t)(qt*128 + w*32 + m*16 + c)*DH + quad*8;
        qf[m][0] = *(const bf16x8*)(qrow);
        qf[m][1] = *(const bf16x8*)(qrow + 32);
    }

    f32x4 Oacc[2][4] = {};
    float lsum[2][4] = {};

    auto stage = [&](int kt, int buf) {
#pragma unroll
        for (int u = 0; u < 2; u++) {            // K segs
            const int seg = w + u*4;             // 0..7
            const int nt = seg >> 1, hh = seg & 1;
            const ushort* g = K + (size_t)(kt*64 + nt*16 + c)*DH + hh*32 + quad*8;
            async16(g, smem + buf*16384 + seg*1024);
        }
#pragma unroll
        for (int u = 0; u < 2; u++) {            // V segs
            const int s2 = w + u*4;              // 0..7
            const int nt = s2 >> 1, kc = s2 & 1;
            const ushort* g = V + (size_t)(nt*16 + c)*NSEQ + kt*64 + kc*32 + quad*8;
            async16(g, smem + buf*16384 + 8192 + s2*1024);
        }
    };

    stage(0, 0);
    stage(1, 1);

    for (int kt = 0; kt < 16; kt++) {
        const int cur = kt % 3;
        if (kt < 15) {
            __asm__ volatile("s_waitcnt vmcnt(4)\n\ts_barrier" ::: "memory");
        } else {
            __asm__ volatile("s_waitcnt vmcnt(0)\n\ts_barrier" ::: "memory");
        }
        if (kt < 14) stage(kt + 2, (kt + 2) % 3);

        const char* Kb = smem + cur*16384;
        const char* Vb = smem + cur*16384 + 8192;

        f32x4 s[2][4];
#pragma unroll
        for (int nt = 0; nt < 4; nt++) {
            bf16x8 k0 = *(const bf16x8*)(Kb + (nt*2+0)*1024 + lane*16);
            bf16x8 k1 = *(const bf16x8*)(Kb + (nt*2+1)*1024 + lane*16);
#pragma unroll
            for (int m = 0; m < 2; m++) {
                f32x4 a = {0.f, 0.f, 0.f, 0.f};
                a = __builtin_amdgcn_mfma_f32_16x16x32_bf16(qf[m][0], k0, a, 0, 0, 0);
                a = __builtin_amdgcn_mfma_f32_16x16x32_bf16(qf[m][1], k1, a, 0, 0, 0);
                s[m][nt] = a;
            }
        }

#pragma unroll
        for (int m = 0; m < 2; m++) {
            ushort (*Psw)[72] = (ushort (*)[72])(smem + ATTN_P_OFF + (w*2+m)*2304);
#pragma unroll
            for (int nt = 0; nt < 4; nt++)
#pragma unroll
                for (int r = 0; r < 4; r++) {
                    const float p = exp2f(s[m][nt][r]);
                    lsum[m][r] += p;
                    Psw[quad*4 + r][nt*16 + c] = (ushort)__builtin_bit_cast(
                        unsigned short, (__bf16)p);
                }
        }
        __asm__ volatile("s_waitcnt lgkmcnt(0)" ::: "memory");

#pragma unroll
        for (int kc = 0; kc < 2; kc++) {
            bf16x8 vfr[4];
#pragma unroll
            for (int nt = 0; nt < 4; nt++)
                vfr[nt] = *(const bf16x8*)(Vb + (nt*2+kc)*1024 + lane*16);
#pragma unroll
            for (int m = 0; m < 2; m++) {
                ushort (*Psw)[72] = (ushort (*)[72])(smem + ATTN_P_OFF + (w*2+m)*2304);
                bf16x8 a = *(const bf16x8*)&Psw[c][kc*32 + quad*8];
#pragma unroll
                for (int nt = 0; nt < 4; nt++)
                    Oacc[m][nt] = __builtin_amdgcn_mfma_f32_16x16x32_bf16(
                        a, vfr[nt], Oacc[m][nt], 0, 0, 0);
            }
        }
        // no trailing barrier: buf cur is only overwritten by stage() issued
        // after the top-of-loop barrier two iterations from now; P region is
        // per-wave (same-wave DS ops complete in order)
    }

#pragma unroll
    for (int mk = 1; mk < 16; mk <<= 1)
#pragma unroll
        for (int m = 0; m < 2; m++)
#pragma unroll
            for (int r = 0; r < 4; r++)
                lsum[m][r] += __shfl_xor(lsum[m][r], mk);

    __syncthreads();
    float (*Osh)[68] = (float (*)[68])smem;   // [128][68]
    {
        float inv[2][4];
#pragma unroll
        for (int m = 0; m < 2; m++)
#pragma unroll
            for (int r = 0; r < 4; r++) inv[m][r] = 1.f / lsum[m][r];
#pragma unroll
        for (int m = 0; m < 2; m++)
#pragma unroll
            for (int nt = 0; nt < 4; nt++)
#pragma unroll
                for (int r = 0; r < 4; r++)
                    Osh[w*32 + m*16 + quad*4 + r][nt*16 + c] =
                        Oacc[m][nt][r] * inv[m][r];
    }
    __syncthreads();

#pragma unroll
    for (int u = 0; u < 8; u++) {
        const int t   = tid + u*256;       // 0..2047
        const int row = t >> 4;            // 0..127
        const int g   = t & 15;
        const int n   = qt*128 + row;
        const float o0 = Osh[row][g*4+0], o1 = Osh[row][g*4+1];
        const float o2 = Osh[row][g*4+2], o3 = Osh[row][g*4+3];
        const float* R = rot   + (size_t)(bb*NSEQ + n)*9;
        const float* T = trans + (size_t)(bb*NSEQ + n)*3;
        const float ti0 = -(R[0]*T[0] + R[3]*T[1] + R[6]*T[2]);
        const float ti1 = -(R[1]*T[0] + R[4]*T[1] + R[7]*T[2]);
        const float ti2 = -(R[2]*T[0] + R[5]*T[1] + R[8]*T[2]);
        const float p0 = R[0]*o0 + R[3]*o1 + R[6]*o2 + ti0*o3;
        const float p1 = R[1]*o0 + R[4]*o1 + R[7]*o2 + ti1*o3;
        const float p2 = R[2]*o0 + R[5]*o1 + R[8]*o2 + ti2*o3;
        const float p3 = o3;
        ushort4 hv = { f2bf(p0), f2bf(p1), f2bf(p2), f2bf(p3) };
        *(ushort4*)(om + (size_t)(bb*NSEQ + n)*INNER + h*DH + g*4) = hv;
    }
}

// ---------------------------------------------------------------------------
// Kernel 3: out^T single-pass bf16 MFMA GEMM: C = woT_bf16 * om_bf16.
// (kept from R14/R15): QUAD-buffered LDS (4 x 16384 = 65536 B), ONE barrier
// per chunk, 3-chunk-deep DMA prefetch (grid = 1 block/CU).
// Epilogue: + bias, fp32 store.
// ---------------------------------------------------------------------------
__global__ __launch_bounds__(256) void out_gemm_mfma(
    const ushort* __restrict__ Ag, const ushort* __restrict__ Bg,
    const float* __restrict__ bias, float* __restrict__ out)
{
    extern __shared__ __align__(16) char smem[];   // 65536 B

    const int tid  = threadIdx.x;
    const int lane = tid & 63;
    const int w    = tid >> 6;
    const int c    = lane & 15;
    const int quad = lane >> 4;
    const int wr   = w >> 1, wc = w & 1;
    const int tn   = blockIdx.x;   // token tile (64)
    const int tf   = blockIdx.y;   // feature tile (4)

    f32x4 acc[4][4] = {};

    // staging roles: part = w>>1 (0=A,1=B), group base = (w&1)*4
    const int part = w >> 1;
    const int g0   = (w & 1) * 4;
    const ushort* src = (part == 0) ? Ag : Bg;
    const ushort* wbase = src + (size_t)((part == 0 ? tf : tn)*128 + g0*16 + c)*INNER
                          + quad*8;

    auto stage = [&](int k0, int buf) {
#pragma unroll
        for (int g = 0; g < 4; g++)
            async16(wbase + (size_t)g*16*INNER + k0,
                    smem + buf*16384 + part*8192 + (g0 + g)*1024);
    };

    stage(0, 0);
    stage(32, 1);
    stage(64, 2);

    for (int ch = 0; ch < 16; ch++) {
        const int cur = ch & 3;
        // chunks in flight after the wait: min(3, 15-ch); 4 DMAs each
        if (ch < 14) {
            __asm__ volatile("s_waitcnt vmcnt(8)\n\ts_barrier" ::: "memory");
        } else if (ch == 14) {
            __asm__ volatile("s_waitcnt vmcnt(4)\n\ts_barrier" ::: "memory");
        } else {
            __asm__ volatile("s_waitcnt vmcnt(0)\n\ts_barrier" ::: "memory");
        }
        if (ch < 13) stage((ch+3)*32, (ch+3) & 3);

        const char* B = smem + cur*16384;
        bf16x8 fa[4], fb[4];
#pragma unroll
        for (int i = 0; i < 4; i++)
            fa[i] = *(const bf16x8*)(B + (wr*4 + i)*1024 + lane*16);
#pragma unroll
        for (int j = 0; j < 4; j++)
            fb[j] = *(const bf16x8*)(B + 8192 + (wc*4 + j)*1024 + lane*16);
#pragma unroll
        for (int i = 0; i < 4; i++)
#pragma unroll
            for (int j = 0; j < 4; j++)
                acc[i][j] = __builtin_amdgcn_mfma_f32_16x16x32_bf16(
                    fa[i], fb[j], acc[i][j], 0, 0, 0);
        // no trailing barrier (4-buffer rotation gates reuse via top barrier)
    }

#pragma unroll
    for (int j = 0; j < 4; j++) {
        const int tc = tn*128 + wc*64 + j*16 + c;
#pragma unroll
        for (int i = 0; i < 4; i++) {
            const int fr = tf*128 + wr*64 + i*16 + quad*4;
            float4 bv = *(const float4*)(bias + fr);
            float4 ov = { acc[i][j][0] + bv.x, acc[i][j][1] + bv.y,
                          acc[i][j][2] + bv.z, acc[i][j][3] + bv.w };
            *(float4*)(out + (size_t)tc*DIM + fr) = ov;
        }
    }
}

extern "C" void kernel_launch(void* const* d_in, const int* in_sizes, int n_in,
                              void* d_out, int out_size, void* d_ws, size_t ws_size,
                              hipStream_t stream) {
    (void)in_sizes; (void)n_in; (void)out_size; (void)ws_size;
    const float* x     = (const float*)d_in[0];
    const float* rot   = (const float*)d_in[1];
    const float* trans = (const float*)d_in[2];
    const float* w_qkv = (const float*)d_in[3];
    const float* b_qkv = (const float*)d_in[4];
    const float* w_out = (const float*)d_in[5];
    const float* b_out = (const float*)d_in[6];
    float* out = (float*)d_out;

    const size_t HB = (size_t)BSZ*NH*NSEQ*DH;        // 4,194,304 elements
    ushort* qb   = (ushort*)d_ws;
    ushort* kb   = qb   + HB;
    ushort* vt   = kb   + HB;                        // [BH][DH][NSEQ]
    ushort* woTh = vt   + HB;                        // [DIM][INNER] bf16
    ushort* wqTh = woTh + (size_t)DIM*INNER;         // [QKVN][DIM] fp16
    ushort* xf   = wqTh + (size_t)QKVN*DIM;          // [NTOK][DIM] fp16
    // om reuses xf (x consumed by kernel 1; om written by kernel 2)
    ushort* om   = xf;

    // dynamic-LDS opt-in for >=64KB — host-side attribute set, not a stream
    // op; safe under graph capture. Idempotent.
    static int s_attr_done = 0;
    if (!s_attr_done) {
        (void)hipFuncSetAttribute((const void*)attn_mfma_kernel,
            hipFuncAttributeMaxDynamicSharedMemorySize, ATTN_LDS);
        (void)hipFuncSetAttribute((const void*)out_gemm_mfma,
            hipFuncAttributeMaxDynamicSharedMemorySize, 65536);
        s_attr_done = 1;
    }

    prep_kernel<<<dim3(5120), 256, 0, stream>>>(
        x, xf, w_qkv, wqTh, w_out, woTh);

    qkv_gemm_f16<<<dim3(NTOK/128, QKVN/128), 256, 32768, stream>>>(
        wqTh, xf, b_qkv, rot, trans, qb, kb, vt);
    attn_mfma_kernel<<<dim3(NSEQ/128, BSZ*NH), 256, ATTN_LDS, stream>>>(
        qb, kb, vt, rot, trans, om);
    out_gemm_mfma<<<dim3(NTOK/128, DIM/128), 256, 65536, stream>>>(
        woTh, om, b_out, out);
}